// Round 3
// baseline (35126.215 us; speedup 1.0000x reference)
//
#include <hip/hip_runtime.h>

#define MUL0 64
#define MUL1 32
#define DFEAT 160

__device__ __constant__ float kINV3 = 0.57735026918962576451f;  // 1/sqrt(3)
__device__ __constant__ float kINV6 = 0.40824829046386301637f;  // 1/sqrt(6)
__device__ __constant__ float kC0   = 0.10206207261596575f;     // 1/sqrt(96)
__device__ __constant__ float kC1   = 0.15309310892394863f;     // sqrt(3/128)
__device__ __constant__ float kLS   = 0.125f;                   // 1/sqrt(64)
__device__ __constant__ float kLV   = 0.17677669529663687f;     // 1/sqrt(32)

// wave-internal LDS producer->consumer fence (wave is lockstep; only need LDS ops drained
// and compiler ordering). Rule #18: sched_barrier after inline-asm waitcnt.
#define WAVE_SYNC() do { \
    __builtin_amdgcn_wave_barrier(); \
    asm volatile("s_waitcnt lgkmcnt(0)" ::: "memory"); \
    __builtin_amdgcn_sched_barrier(0); \
} while (0)

// 4 edges per WAVE, register-blocked. Weights in LDS (block-shared), x-rows staged
// transposed per-wave so one broadcast ds_read_b128 serves 4 edges.
__global__ __launch_bounds__(256) void edge_kernel(
    const float* __restrict__ x, const float* __restrict__ sh,
    const float* __restrict__ W1, const float* __restrict__ W2,
    const float* __restrict__ W3, const float* __restrict__ W4,
    const float* __restrict__ W5,
    const int* __restrict__ src, const int* __restrict__ dst,
    float* __restrict__ magg, int E)
{
    __shared__ float sW1[64 * 64];
    __shared__ float sW2[32 * 64];
    __shared__ float sW3[64 * 32];
    __shared__ float sW4[32 * 32];
    __shared__ float sW5[32 * 32];
    __shared__ float4 sS[4][64];      // [wave][u] -> ss[u] for edges q=0..3
    __shared__ float4 sV[4][32][3];   // [wave][u][comp] -> v[u][comp] for q=0..3

    const int tid = threadIdx.x;
    for (int i = tid; i < 64 * 64; i += 256) sW1[i] = W1[i];
    for (int i = tid; i < 32 * 64; i += 256) sW2[i] = W2[i];
    for (int i = tid; i < 64 * 32; i += 256) sW3[i] = W3[i];
    for (int i = tid; i < 32 * 32; i += 256) sW4[i] = W4[i];
    for (int i = tid; i < 32 * 32; i += 256) sW5[i] = W5[i];
    __syncthreads();

    const int lane = tid & 63;
    const int wid  = tid >> 6;
    const int w    = lane & 31;
    const int h    = lane >> 5;       // this half handles edges {2h, 2h+1} for out1

    const int ngroups = (E + 3) >> 2;
    const int gw = blockIdx.x * 4 + wid;
    const int gstride = gridDim.x * 4;

    for (int g = gw; g < ngroups; g += gstride) {
        const int ebase = g << 2;

        int   didx[4];
        float e0q[4], e1xq[4], e1yq[4], e1zq[4];

        #pragma unroll
        for (int q = 0; q < 4; ++q) {
            const int e = ebase + q;
            if (e < E) {
                didx[q] = dst[e];
                const float4 she = ((const float4*)sh)[e];
                e0q[q] = she.x; e1xq[q] = she.y; e1yq[q] = she.z; e1zq[q] = she.w;
                const float* xr = x + (size_t)src[e] * DFEAT;
                #pragma unroll
                for (int t0 = 0; t0 < 3; ++t0) {
                    const int t = lane + 64 * t0;
                    if (t < DFEAT) {
                        const float val = xr[t];
                        if (t < 64) {
                            ((float*)&sS[wid][t])[q] = val;
                        } else {
                            const int r = t - 64;
                            ((float*)&sV[wid][r / 3][r % 3])[q] = val;
                        }
                    }
                }
            } else {
                didx[q] = -1;
                e0q[q] = 0.f; e1xq[q] = 0.f; e1yq[q] = 0.f; e1zq[q] = 0.f;
            }
        }
        WAVE_SYNC();

        // ---- acc1[q] = (ss_q @ W1)[lane], acc2[q] = (dot_q @ W2)[lane]
        float acc1[4] = {0.f, 0.f, 0.f, 0.f};
        float acc2[4] = {0.f, 0.f, 0.f, 0.f};
        #pragma unroll
        for (int u = 0; u < 64; ++u) {
            const float w1 = sW1[u * 64 + lane];
            const float4 s4 = sS[wid][u];
            acc1[0] += s4.x * w1; acc1[1] += s4.y * w1;
            acc1[2] += s4.z * w1; acc1[3] += s4.w * w1;
        }
        #pragma unroll
        for (int u = 0; u < 32; ++u) {
            const float w2 = sW2[u * 64 + lane];
            const float4 vx = sV[wid][u][0];
            const float4 vy = sV[wid][u][1];
            const float4 vz = sV[wid][u][2];
            acc2[0] += (vx.x * e1xq[0] + vy.x * e1yq[0] + vz.x * e1zq[0]) * w2;
            acc2[1] += (vx.y * e1xq[1] + vy.y * e1yq[1] + vz.y * e1zq[1]) * w2;
            acc2[2] += (vx.z * e1xq[2] + vy.z * e1yq[2] + vz.z * e1zq[2]) * w2;
            acc2[3] += (vx.w * e1xq[3] + vy.w * e1yq[3] + vz.w * e1zq[3]) * w2;
        }

        // ---- acc3[p] = (ss_{2h+p} @ W3)[w]
        float acc3[2] = {0.f, 0.f};
        #pragma unroll
        for (int u = 0; u < 64; ++u) {
            const float w3 = sW3[u * 32 + w];
            const float4 s4 = sS[wid][u];
            const float s0 = h ? s4.z : s4.x;
            const float s1 = h ? s4.w : s4.y;
            acc3[0] += s0 * w3;
            acc3[1] += s1 * w3;
        }

        // per-half edge constants (constant-indexed selects only)
        const float e0h[2]  = { h ? e0q[2]  : e0q[0],  h ? e0q[3]  : e0q[1]  };
        const float e1xh[2] = { h ? e1xq[2] : e1xq[0], h ? e1xq[3] : e1xq[1] };
        const float e1yh[2] = { h ? e1yq[2] : e1yq[0], h ? e1yq[3] : e1yq[1] };
        const float e1zh[2] = { h ? e1zq[2] : e1zq[0], h ? e1zq[3] : e1zq[1] };

        // ---- accb[p][i] = (v_i @ W4)[w], accc[p][i] = (cross(v,e1)_i @ W5)[w]
        float accb[2][3] = {{0.f,0.f,0.f},{0.f,0.f,0.f}};
        float accc[2][3] = {{0.f,0.f,0.f},{0.f,0.f,0.f}};
        #pragma unroll
        for (int u = 0; u < 32; ++u) {
            const float w4 = sW4[u * 32 + w];
            const float w5 = sW5[u * 32 + w];
            const float4 vx4 = sV[wid][u][0];
            const float4 vy4 = sV[wid][u][1];
            const float4 vz4 = sV[wid][u][2];
            const float vxp[2] = { h ? vx4.z : vx4.x, h ? vx4.w : vx4.y };
            const float vyp[2] = { h ? vy4.z : vy4.x, h ? vy4.w : vy4.y };
            const float vzp[2] = { h ? vz4.z : vz4.x, h ? vz4.w : vz4.y };
            #pragma unroll
            for (int p = 0; p < 2; ++p) {
                accb[p][0] += vxp[p] * w4;
                accb[p][1] += vyp[p] * w4;
                accb[p][2] += vzp[p] * w4;
                const float cx = vyp[p] * e1zh[p] - vzp[p] * e1yh[p];
                const float cy = vzp[p] * e1xh[p] - vxp[p] * e1zh[p];
                const float cz = vxp[p] * e1yh[p] - vyp[p] * e1xh[p];
                accc[p][0] += cx * w5;
                accc[p][1] += cy * w5;
                accc[p][2] += cz * w5;
            }
        }
        WAVE_SYNC();  // all LDS reads done before next iteration's staging overwrites

        // ---- scatter out0
        #pragma unroll
        for (int q = 0; q < 4; ++q) {
            if (didx[q] >= 0) {
                const float o0 = kC0 * (e0q[q] * acc1[q] + kINV3 * acc2[q]);
                atomicAdd(&magg[(size_t)didx[q] * DFEAT + lane], o0);
            }
        }
        // ---- scatter out1
        #pragma unroll
        for (int p = 0; p < 2; ++p) {
            const int dd = h ? didx[2 + p] : didx[p];
            if (dd >= 0) {
                const float b3 = kC1 * kINV3 * acc3[p];
                const float b4 = kC1 * kINV3 * e0h[p];
                const float o1x = e1xh[p] * b3 + b4 * accb[p][0] + kC1 * kINV6 * accc[p][0];
                const float o1y = e1yh[p] * b3 + b4 * accb[p][1] + kC1 * kINV6 * accc[p][1];
                const float o1z = e1zh[p] * b3 + b4 * accb[p][2] + kC1 * kINV6 * accc[p][2];
                float* dstp = &magg[(size_t)dd * DFEAT + 64 + 3 * w];
                atomicAdd(dstp + 0, o1x);
                atomicAdd(dstp + 1, o1y);
                atomicAdd(dstp + 2, o1z);
            }
        }
    }
}

// One wave per node: h = [m_s@Ws*LS ; (m_v@Wv)*LV], out = x + relu(h)
__global__ __launch_bounds__(256) void node_kernel(
    const float* __restrict__ x, const float* __restrict__ magg,
    const float* __restrict__ Ws, const float* __restrict__ Wv,
    float* __restrict__ out, int N)
{
    __shared__ float sWs[64 * 64];
    __shared__ float sWv[32 * 32];
    __shared__ float sM[4][DFEAT];

    const int tid = threadIdx.x;
    for (int i = tid; i < 64 * 64; i += 256) sWs[i] = Ws[i];
    for (int i = tid; i < 32 * 32; i += 256) sWv[i] = Wv[i];
    __syncthreads();

    const int lane = tid & 63;
    const int wid  = tid >> 6;

    for (int base = blockIdx.x * 4; base < N; base += gridDim.x * 4) {
        const int n = base + wid;
        const bool active = (n < N);
        if (active) {
            const float4* mr = (const float4*)(magg + (size_t)n * DFEAT);
            if (lane < 40) ((float4*)sM[wid])[lane] = mr[lane];
        }
        __syncthreads();
        if (active) {
            const float* ms = sM[wid];
            const float* mv = sM[wid] + 64;
            const size_t o = (size_t)n * DFEAT;

            float acc = 0.f;
            #pragma unroll
            for (int u = 0; u < 64; ++u) acc += ms[u] * sWs[u * 64 + lane];
            const float hs = kLS * acc;
            out[o + lane] = x[o + lane] + fmaxf(hs, 0.f);

            const int w = lane & 31;
            {
                const int i0 = lane >> 5;
                float a = 0.f;
                #pragma unroll
                for (int u = 0; u < 32; ++u) a += mv[3 * u + i0] * sWv[u * 32 + w];
                const float hv = kLV * a;
                out[o + 64 + 3 * w + i0] = x[o + 64 + 3 * w + i0] + fmaxf(hv, 0.f);
            }
            if (lane < 32) {
                float a = 0.f;
                #pragma unroll
                for (int u = 0; u < 32; ++u) a += mv[3 * u + 2] * sWv[u * 32 + w];
                const float hv = kLV * a;
                out[o + 64 + 3 * w + 2] = x[o + 64 + 3 * w + 2] + fmaxf(hv, 0.f);
            }
        }
        __syncthreads();
    }
}

extern "C" void kernel_launch(void* const* d_in, const int* in_sizes, int n_in,
                              void* d_out, int out_size, void* d_ws, size_t ws_size,
                              hipStream_t stream) {
    const float* x  = (const float*)d_in[0];
    const float* sh = (const float*)d_in[1];
    const float* W1 = (const float*)d_in[2];
    const float* W2 = (const float*)d_in[3];
    const float* W3 = (const float*)d_in[4];
    const float* W4 = (const float*)d_in[5];
    const float* W5 = (const float*)d_in[6];
    const float* Ws = (const float*)d_in[7];
    const float* Wv = (const float*)d_in[8];
    const int*   ei = (const int*)d_in[9];

    const int E = in_sizes[9] / 2;
    const int N = in_sizes[0] / DFEAT;
    const int* src = ei;
    const int* dst = ei + E;

    float* magg = (float*)d_ws;  // N*160 floats = 32 MB
    hipMemsetAsync(magg, 0, (size_t)N * DFEAT * sizeof(float), stream);

    edge_kernel<<<768, 256, 0, stream>>>(x, sh, W1, W2, W3, W4, W5, src, dst, magg, E);
    node_kernel<<<1024, 256, 0, stream>>>(x, magg, Ws, Wv, (float*)d_out, N);
}

// Round 4
// 6957.881 us; speedup vs baseline: 5.0484x; 5.0484x over previous
//
#include <hip/hip_runtime.h>

#define MUL0 64
#define MUL1 32
#define DFEAT 160

__device__ __constant__ float kINV3 = 0.57735026918962576451f;  // 1/sqrt(3)
__device__ __constant__ float kINV6 = 0.40824829046386301637f;  // 1/sqrt(6)
__device__ __constant__ float kC0   = 0.10206207261596575f;     // 1/sqrt(96)
__device__ __constant__ float kC1   = 0.15309310892394863f;     // sqrt(3/128)
__device__ __constant__ float kLS   = 0.125f;                   // 1/sqrt(64)
__device__ __constant__ float kLV   = 0.17677669529663687f;     // 1/sqrt(32)

// wave-internal LDS fence: drain LDS ops + block compiler motion (rule #18)
#define WAVE_SYNC() do { \
    asm volatile("s_waitcnt lgkmcnt(0)" ::: "memory"); \
    __builtin_amdgcn_sched_barrier(0); \
} while (0)

// Tile of 16 edges per wave; lane = (edge e = lane&15, part p = lane>>4).
// x-rows staged transposed in LDS [160][16]; weights in LDS, float4-broadcast.
__global__ __launch_bounds__(256) void edge_kernel(
    const float* __restrict__ x, const float* __restrict__ sh,
    const float* __restrict__ W1, const float* __restrict__ W2,
    const float* __restrict__ W3, const float* __restrict__ W4,
    const float* __restrict__ W5,
    const int* __restrict__ src, const int* __restrict__ dst,
    float* __restrict__ magg, int E)
{
    __shared__ float sW1[64 * 64];
    __shared__ float sW2[32 * 64];
    __shared__ float sW3[64 * 32];
    __shared__ float sW4[32 * 32];
    __shared__ float sW5[32 * 32];
    __shared__ float sX[4][DFEAT][16];   // [wave][elem][edge]

    const int tid = threadIdx.x;
    for (int i = tid; i < 64 * 64; i += 256) sW1[i] = W1[i];
    for (int i = tid; i < 32 * 64; i += 256) sW2[i] = W2[i];
    for (int i = tid; i < 64 * 32; i += 256) sW3[i] = W3[i];
    for (int i = tid; i < 32 * 32; i += 256) sW4[i] = W4[i];
    for (int i = tid; i < 32 * 32; i += 256) sW5[i] = W5[i];
    __syncthreads();

    const float4* W1v = (const float4*)sW1;  // [u*16 + p*4 + k]
    const float4* W2v = (const float4*)sW2;  // [u*16 + p*4 + k]
    const float4* W3v = (const float4*)sW3;  // [u*8  + p*2 + k]
    const float4* W4v = (const float4*)sW4;  // [u*8  + p*2 + k]
    const float4* W5v = (const float4*)sW5;  // [u*8  + p*2 + k]

    const int lane = tid & 63;
    const int wid  = tid >> 6;
    const int e    = lane & 15;   // edge within tile
    const int p    = lane >> 4;   // channel part 0..3
    const int est  = lane >> 2;   // staging edge
    const int q0   = lane & 3;    // staging quad phase

    const int ntiles = (E + 15) >> 4;
    for (int tile = blockIdx.x * 4 + wid; tile < ntiles; tile += gridDim.x * 4) {
        const int ebase = tile << 4;

        // per-lane edge metadata (4 lanes share an edge -> broadcast loads)
        const int eidx = ebase + e;
        const int ecl  = (eidx < E) ? eidx : (E - 1);
        const int didx = (eidx < E) ? dst[ecl] : -1;
        const float4 she = ((const float4*)sh)[ecl];
        const float e0 = she.x, e1x = she.y, e1y = she.z, e1z = she.w;

        // ---- stage 16 x-rows transposed: lane stages 10 float4 of edge `est`
        {
            const int scl = ((ebase + est) < E) ? (ebase + est) : (E - 1);
            const float4* xr = (const float4*)(x + (size_t)src[scl] * DFEAT);
            #pragma unroll
            for (int t = 0; t < 10; ++t) {
                const int quad = q0 + 4 * t;     // 0..39
                const float4 v4 = xr[quad];
                const int r = quad * 4;
                sX[wid][r + 0][est] = v4.x;
                sX[wid][r + 1][est] = v4.y;
                sX[wid][r + 2][est] = v4.z;
                sX[wid][r + 3][est] = v4.w;
            }
        }
        WAVE_SYNC();

        // ---- phase A: acc1[j] = (ss @ W1)[p*16+j], sw3[j] = (ss @ W3)[p*8+j]
        float acc1[16];
        float sw3[8];
        #pragma unroll
        for (int j = 0; j < 16; ++j) acc1[j] = 0.f;
        #pragma unroll
        for (int j = 0; j < 8; ++j) sw3[j] = 0.f;

        #pragma unroll 8
        for (int u = 0; u < 64; ++u) {
            const float ssu = sX[wid][u][e];
            #pragma unroll
            for (int k = 0; k < 4; ++k) {
                const float4 wv = W1v[u * 16 + p * 4 + k];
                acc1[4 * k + 0] += ssu * wv.x;
                acc1[4 * k + 1] += ssu * wv.y;
                acc1[4 * k + 2] += ssu * wv.z;
                acc1[4 * k + 3] += ssu * wv.w;
            }
            #pragma unroll
            for (int k = 0; k < 2; ++k) {
                const float4 wv = W3v[u * 8 + p * 2 + k];
                sw3[4 * k + 0] += ssu * wv.x;
                sw3[4 * k + 1] += ssu * wv.y;
                sw3[4 * k + 2] += ssu * wv.z;
                sw3[4 * k + 3] += ssu * wv.w;
            }
        }

        // ---- phase B1: acc2[j] = (dot @ W2)[p*16+j]
        float acc2[16];
        #pragma unroll
        for (int j = 0; j < 16; ++j) acc2[j] = 0.f;

        #pragma unroll 4
        for (int u = 0; u < 32; ++u) {
            const float vx = sX[wid][64 + 3 * u + 0][e];
            const float vy = sX[wid][64 + 3 * u + 1][e];
            const float vz = sX[wid][64 + 3 * u + 2][e];
            const float du = vx * e1x + vy * e1y + vz * e1z;
            #pragma unroll
            for (int k = 0; k < 4; ++k) {
                const float4 wv = W2v[u * 16 + p * 4 + k];
                acc2[4 * k + 0] += du * wv.x;
                acc2[4 * k + 1] += du * wv.y;
                acc2[4 * k + 2] += du * wv.z;
                acc2[4 * k + 3] += du * wv.w;
            }
        }

        // ---- flush out0
        if (didx >= 0) {
            float* b = magg + (size_t)didx * DFEAT + p * 16;
            #pragma unroll
            for (int j = 0; j < 16; ++j)
                atomicAdd(b + j, kC0 * (e0 * acc1[j] + kINV3 * acc2[j]));
        }

        // ---- phase B2: accW4_i[j] = (v_i @ W4)[p*8+j], accW5_i[j] = (cross_i @ W5)[p*8+j]
        float a4x[8], a4y[8], a4z[8], a5x[8], a5y[8], a5z[8];
        #pragma unroll
        for (int j = 0; j < 8; ++j) { a4x[j]=0.f; a4y[j]=0.f; a4z[j]=0.f; a5x[j]=0.f; a5y[j]=0.f; a5z[j]=0.f; }

        #pragma unroll 4
        for (int u = 0; u < 32; ++u) {
            const float vx = sX[wid][64 + 3 * u + 0][e];
            const float vy = sX[wid][64 + 3 * u + 1][e];
            const float vz = sX[wid][64 + 3 * u + 2][e];
            const float cx = vy * e1z - vz * e1y;
            const float cy = vz * e1x - vx * e1z;
            const float cz = vx * e1y - vy * e1x;
            #pragma unroll
            for (int k = 0; k < 2; ++k) {
                const float4 w4 = W4v[u * 8 + p * 2 + k];
                const float4 w5 = W5v[u * 8 + p * 2 + k];
                a4x[4*k+0] += vx * w4.x;  a4x[4*k+1] += vx * w4.y;  a4x[4*k+2] += vx * w4.z;  a4x[4*k+3] += vx * w4.w;
                a4y[4*k+0] += vy * w4.x;  a4y[4*k+1] += vy * w4.y;  a4y[4*k+2] += vy * w4.z;  a4y[4*k+3] += vy * w4.w;
                a4z[4*k+0] += vz * w4.x;  a4z[4*k+1] += vz * w4.y;  a4z[4*k+2] += vz * w4.z;  a4z[4*k+3] += vz * w4.w;
                a5x[4*k+0] += cx * w5.x;  a5x[4*k+1] += cx * w5.y;  a5x[4*k+2] += cx * w5.z;  a5x[4*k+3] += cx * w5.w;
                a5y[4*k+0] += cy * w5.x;  a5y[4*k+1] += cy * w5.y;  a5y[4*k+2] += cy * w5.z;  a5y[4*k+3] += cy * w5.w;
                a5z[4*k+0] += cz * w5.x;  a5z[4*k+1] += cz * w5.y;  a5z[4*k+2] += cz * w5.z;  a5z[4*k+3] += cz * w5.w;
            }
        }

        // ---- flush out1: out1[w][i] = C1*(INV3*(e1_i*sw3 + e0*a4_i) + INV6*a5_i), w = p*8+j
        if (didx >= 0) {
            float* b = magg + (size_t)didx * DFEAT + 64 + 3 * (p * 8);
            #pragma unroll
            for (int j = 0; j < 8; ++j) {
                const float o1x = kC1 * (kINV3 * (e1x * sw3[j] + e0 * a4x[j]) + kINV6 * a5x[j]);
                const float o1y = kC1 * (kINV3 * (e1y * sw3[j] + e0 * a4y[j]) + kINV6 * a5y[j]);
                const float o1z = kC1 * (kINV3 * (e1z * sw3[j] + e0 * a4z[j]) + kINV6 * a5z[j]);
                atomicAdd(b + 3 * j + 0, o1x);
                atomicAdd(b + 3 * j + 1, o1y);
                atomicAdd(b + 3 * j + 2, o1z);
            }
        }
        WAVE_SYNC();  // all sX reads done before next iteration overwrites
    }
}

// One wave per node: h = [m_s@Ws*LS ; (m_v@Wv)*LV], out = x + relu(h)
__global__ __launch_bounds__(256) void node_kernel(
    const float* __restrict__ x, const float* __restrict__ magg,
    const float* __restrict__ Ws, const float* __restrict__ Wv,
    float* __restrict__ out, int N)
{
    __shared__ float sWs[64 * 64];
    __shared__ float sWv[32 * 32];
    __shared__ float sM[4][DFEAT];

    const int tid = threadIdx.x;
    for (int i = tid; i < 64 * 64; i += 256) sWs[i] = Ws[i];
    for (int i = tid; i < 32 * 32; i += 256) sWv[i] = Wv[i];
    __syncthreads();

    const int lane = tid & 63;
    const int wid  = tid >> 6;

    for (int base = blockIdx.x * 4; base < N; base += gridDim.x * 4) {
        const int n = base + wid;
        const bool active = (n < N);
        if (active) {
            const float4* mr = (const float4*)(magg + (size_t)n * DFEAT);
            if (lane < 40) ((float4*)sM[wid])[lane] = mr[lane];
        }
        __syncthreads();
        if (active) {
            const float* ms = sM[wid];
            const float* mv = sM[wid] + 64;
            const size_t o = (size_t)n * DFEAT;

            float acc = 0.f;
            #pragma unroll
            for (int u = 0; u < 64; ++u) acc += ms[u] * sWs[u * 64 + lane];
            out[o + lane] = x[o + lane] + fmaxf(kLS * acc, 0.f);

            const int w = lane & 31;
            {
                const int i0 = lane >> 5;
                float a = 0.f;
                #pragma unroll
                for (int u = 0; u < 32; ++u) a += mv[3 * u + i0] * sWv[u * 32 + w];
                out[o + 64 + 3 * w + i0] = x[o + 64 + 3 * w + i0] + fmaxf(kLV * a, 0.f);
            }
            if (lane < 32) {
                float a = 0.f;
                #pragma unroll
                for (int u = 0; u < 32; ++u) a += mv[3 * u + 2] * sWv[u * 32 + w];
                out[o + 64 + 3 * w + 2] = x[o + 64 + 3 * w + 2] + fmaxf(kLV * a, 0.f);
            }
        }
        __syncthreads();
    }
}

extern "C" void kernel_launch(void* const* d_in, const int* in_sizes, int n_in,
                              void* d_out, int out_size, void* d_ws, size_t ws_size,
                              hipStream_t stream) {
    const float* x  = (const float*)d_in[0];
    const float* sh = (const float*)d_in[1];
    const float* W1 = (const float*)d_in[2];
    const float* W2 = (const float*)d_in[3];
    const float* W3 = (const float*)d_in[4];
    const float* W4 = (const float*)d_in[5];
    const float* W5 = (const float*)d_in[6];
    const float* Ws = (const float*)d_in[7];
    const float* Wv = (const float*)d_in[8];
    const int*   ei = (const int*)d_in[9];

    const int E = in_sizes[9] / 2;
    const int N = in_sizes[0] / DFEAT;
    const int* src = ei;
    const int* dst = ei + E;

    float* magg = (float*)d_ws;  // N*160 floats = 32 MB
    hipMemsetAsync(magg, 0, (size_t)N * DFEAT * sizeof(float), stream);

    edge_kernel<<<1024, 256, 0, stream>>>(x, sh, W1, W2, W3, W4, W5, src, dst, magg, E);
    node_kernel<<<1024, 256, 0, stream>>>(x, magg, Ws, Wv, (float*)d_out, N);
}

// Round 5
// 715.910 us; speedup vs baseline: 49.0651x; 9.7189x over previous
//
#include <hip/hip_runtime.h>

#define MUL0 64
#define MUL1 32
#define DFEAT 160

__device__ __constant__ float kINV3 = 0.57735026918962576451f;  // 1/sqrt(3)
__device__ __constant__ float kINV6 = 0.40824829046386301637f;  // 1/sqrt(6)
__device__ __constant__ float kC0   = 0.10206207261596575f;     // 1/sqrt(96)
__device__ __constant__ float kC1   = 0.15309310892394863f;     // sqrt(3/128)
__device__ __constant__ float kLS   = 0.125f;                   // 1/sqrt(64)
__device__ __constant__ float kLV   = 0.17677669529663687f;     // 1/sqrt(32)

// wave-internal LDS fence: drain LDS ops + block compiler motion (rule #18)
#define WAVE_SYNC() do { \
    asm volatile("s_waitcnt lgkmcnt(0)" ::: "memory"); \
    __builtin_amdgcn_sched_barrier(0); \
} while (0)

// Tile of 16 edges per wave; lane = (edge e = lane&15, part p = lane>>4).
// Compute as round 4 (proven); scatter via LDS transpose so each atomic
// instruction has 64-lane-contiguous addresses (coalesced sectors).
__global__ __launch_bounds__(256) void edge_kernel(
    const float* __restrict__ x, const float* __restrict__ sh,
    const float* __restrict__ W1, const float* __restrict__ W2,
    const float* __restrict__ W3, const float* __restrict__ W4,
    const float* __restrict__ W5,
    const int* __restrict__ src, const int* __restrict__ dst,
    float* __restrict__ magg, int E)
{
    __shared__ float sW1[64 * 64];
    __shared__ float sW2[32 * 64];
    __shared__ float sW3[64 * 32];
    __shared__ float sW4[32 * 32];
    __shared__ float sW5[32 * 32];
    __shared__ float sX[4][DFEAT * 16];   // per-wave slab: 2560 floats

    const int tid = threadIdx.x;
    for (int i = tid; i < 64 * 64; i += 256) sW1[i] = W1[i];
    for (int i = tid; i < 32 * 64; i += 256) sW2[i] = W2[i];
    for (int i = tid; i < 64 * 32; i += 256) sW3[i] = W3[i];
    for (int i = tid; i < 32 * 32; i += 256) sW4[i] = W4[i];
    for (int i = tid; i < 32 * 32; i += 256) sW5[i] = W5[i];
    __syncthreads();

    const float4* W1v = (const float4*)sW1;  // [u*16 + p*4 + k]
    const float4* W2v = (const float4*)sW2;  // [u*16 + p*4 + k]
    const float4* W3v = (const float4*)sW3;  // [u*8  + p*2 + k]
    const float4* W4v = (const float4*)sW4;  // [u*8  + p*2 + k]
    const float4* W5v = (const float4*)sW5;  // [u*8  + p*2 + k]

    const int lane = tid & 63;
    const int wid  = tid >> 6;
    const int e    = lane & 15;   // edge within tile
    const int p    = lane >> 4;   // channel part 0..3
    const int est  = lane >> 2;   // staging edge
    const int q0   = lane & 3;    // staging quad phase
    float* slab = sX[wid];

    const int ntiles = (E + 15) >> 4;
    for (int tile = blockIdx.x * 4 + wid; tile < ntiles; tile += gridDim.x * 4) {
        const int ebase = tile << 4;

        const int eidx = ebase + e;
        const int ecl  = (eidx < E) ? eidx : (E - 1);
        const int didx = (eidx < E) ? dst[ecl] : -1;
        const float4 she = ((const float4*)sh)[ecl];
        const float e0 = she.x, e1x = she.y, e1y = she.z, e1z = she.w;

        // ---- stage 16 x-rows transposed: slab[r*16 + edge]
        {
            const int se  = ebase + est;
            const int scl = (se < E) ? se : (E - 1);
            const float4* xr = (const float4*)(x + (size_t)src[scl] * DFEAT);
            #pragma unroll
            for (int t = 0; t < 10; ++t) {
                const int quad = q0 + 4 * t;     // 0..39
                const float4 v4 = xr[quad];
                const int r = quad * 4;
                slab[(r + 0) * 16 + est] = v4.x;
                slab[(r + 1) * 16 + est] = v4.y;
                slab[(r + 2) * 16 + est] = v4.z;
                slab[(r + 3) * 16 + est] = v4.w;
            }
        }
        WAVE_SYNC();

        // ---- phase A: acc1[j] = (ss @ W1)[p*16+j], sw3[j] = (ss @ W3)[p*8+j]
        float acc1[16];
        float sw3[8];
        #pragma unroll
        for (int j = 0; j < 16; ++j) acc1[j] = 0.f;
        #pragma unroll
        for (int j = 0; j < 8; ++j) sw3[j] = 0.f;

        #pragma unroll 8
        for (int u = 0; u < 64; ++u) {
            const float ssu = slab[u * 16 + e];
            #pragma unroll
            for (int k = 0; k < 4; ++k) {
                const float4 wv = W1v[u * 16 + p * 4 + k];
                acc1[4 * k + 0] += ssu * wv.x;
                acc1[4 * k + 1] += ssu * wv.y;
                acc1[4 * k + 2] += ssu * wv.z;
                acc1[4 * k + 3] += ssu * wv.w;
            }
            #pragma unroll
            for (int k = 0; k < 2; ++k) {
                const float4 wv = W3v[u * 8 + p * 2 + k];
                sw3[4 * k + 0] += ssu * wv.x;
                sw3[4 * k + 1] += ssu * wv.y;
                sw3[4 * k + 2] += ssu * wv.z;
                sw3[4 * k + 3] += ssu * wv.w;
            }
        }

        // ---- phase B1: acc2[j] = (dot @ W2)[p*16+j]
        float acc2[16];
        #pragma unroll
        for (int j = 0; j < 16; ++j) acc2[j] = 0.f;

        #pragma unroll 4
        for (int u = 0; u < 32; ++u) {
            const float vx = slab[(64 + 3 * u + 0) * 16 + e];
            const float vy = slab[(64 + 3 * u + 1) * 16 + e];
            const float vz = slab[(64 + 3 * u + 2) * 16 + e];
            const float du = vx * e1x + vy * e1y + vz * e1z;
            #pragma unroll
            for (int k = 0; k < 4; ++k) {
                const float4 wv = W2v[u * 16 + p * 4 + k];
                acc2[4 * k + 0] += du * wv.x;
                acc2[4 * k + 1] += du * wv.y;
                acc2[4 * k + 2] += du * wv.z;
                acc2[4 * k + 3] += du * wv.w;
            }
        }
        WAVE_SYNC();  // phase-A ss reads done before overwriting rows 0..63

        // ---- out0 tile [16][64] over slab[0..1023], col-swizzle (c+e)&63
        #pragma unroll
        for (int j = 0; j < 16; ++j) {
            const int c = 16 * p + j;
            slab[64 * e + ((c + e) & 63)] = kC0 * (e0 * acc1[j] + kINV3 * acc2[j]);
        }
        WAVE_SYNC();
        // ---- flush out0: per edge q, 64 contiguous lanes -> coalesced atomics
        for (int q = 0; q < 16; ++q) {
            const int dq = __builtin_amdgcn_readlane(didx, q);
            if (dq >= 0) {
                const float v = slab[64 * q + ((lane + q) & 63)];
                atomicAdd(&magg[(size_t)dq * DFEAT + lane], v);
            }
        }

        // ---- phase B2 (reads v region rows 64..159 only; disjoint from out0 tile)
        float a4x[8], a4y[8], a4z[8], a5x[8], a5y[8], a5z[8];
        #pragma unroll
        for (int j = 0; j < 8; ++j) { a4x[j]=0.f; a4y[j]=0.f; a4z[j]=0.f; a5x[j]=0.f; a5y[j]=0.f; a5z[j]=0.f; }

        #pragma unroll 4
        for (int u = 0; u < 32; ++u) {
            const float vx = slab[(64 + 3 * u + 0) * 16 + e];
            const float vy = slab[(64 + 3 * u + 1) * 16 + e];
            const float vz = slab[(64 + 3 * u + 2) * 16 + e];
            const float cx = vy * e1z - vz * e1y;
            const float cy = vz * e1x - vx * e1z;
            const float cz = vx * e1y - vy * e1x;
            #pragma unroll
            for (int k = 0; k < 2; ++k) {
                const float4 w4 = W4v[u * 8 + p * 2 + k];
                const float4 w5 = W5v[u * 8 + p * 2 + k];
                a4x[4*k+0] += vx * w4.x;  a4x[4*k+1] += vx * w4.y;  a4x[4*k+2] += vx * w4.z;  a4x[4*k+3] += vx * w4.w;
                a4y[4*k+0] += vy * w4.x;  a4y[4*k+1] += vy * w4.y;  a4y[4*k+2] += vy * w4.z;  a4y[4*k+3] += vy * w4.w;
                a4z[4*k+0] += vz * w4.x;  a4z[4*k+1] += vz * w4.y;  a4z[4*k+2] += vz * w4.z;  a4z[4*k+3] += vz * w4.w;
                a5x[4*k+0] += cx * w5.x;  a5x[4*k+1] += cx * w5.y;  a5x[4*k+2] += cx * w5.z;  a5x[4*k+3] += cx * w5.w;
                a5y[4*k+0] += cy * w5.x;  a5y[4*k+1] += cy * w5.y;  a5y[4*k+2] += cy * w5.z;  a5y[4*k+3] += cy * w5.w;
                a5z[4*k+0] += cz * w5.x;  a5z[4*k+1] += cz * w5.y;  a5z[4*k+2] += cz * w5.z;  a5z[4*k+3] += cz * w5.w;
            }
        }
        WAVE_SYNC();  // v reads + out0 flush reads done before out1 tile overwrite

        // ---- out1 tile [16][97] over slab[0..1551] (97 stride -> conflict-free)
        #pragma unroll
        for (int j = 0; j < 8; ++j) {
            const int wch = p * 8 + j;
            const float o1x = kC1 * (kINV3 * (e1x * sw3[j] + e0 * a4x[j]) + kINV6 * a5x[j]);
            const float o1y = kC1 * (kINV3 * (e1y * sw3[j] + e0 * a4y[j]) + kINV6 * a5y[j]);
            const float o1z = kC1 * (kINV3 * (e1z * sw3[j] + e0 * a4z[j]) + kINV6 * a5z[j]);
            slab[97 * e + 3 * wch + 0] = o1x;
            slab[97 * e + 3 * wch + 1] = o1y;
            slab[97 * e + 3 * wch + 2] = o1z;
        }
        WAVE_SYNC();
        // ---- flush out1: per edge q, contiguous lanes over channels 64..159
        for (int q = 0; q < 16; ++q) {
            const int dq = __builtin_amdgcn_readlane(didx, q);
            if (dq >= 0) {
                float* b = &magg[(size_t)dq * DFEAT + 64];
                atomicAdd(b + lane, slab[97 * q + lane]);
                if (lane < 32)
                    atomicAdd(b + 64 + lane, slab[97 * q + 64 + lane]);
            }
        }
        WAVE_SYNC();  // flush reads done before next tile's staging overwrites
    }
}

// One wave per node: h = [m_s@Ws*LS ; (m_v@Wv)*LV], out = x + relu(h)
__global__ __launch_bounds__(256) void node_kernel(
    const float* __restrict__ x, const float* __restrict__ magg,
    const float* __restrict__ Ws, const float* __restrict__ Wv,
    float* __restrict__ out, int N)
{
    __shared__ float sWs[64 * 64];
    __shared__ float sWv[32 * 32];
    __shared__ float sM[4][DFEAT];

    const int tid = threadIdx.x;
    for (int i = tid; i < 64 * 64; i += 256) sWs[i] = Ws[i];
    for (int i = tid; i < 32 * 32; i += 256) sWv[i] = Wv[i];
    __syncthreads();

    const int lane = tid & 63;
    const int wid  = tid >> 6;

    for (int base = blockIdx.x * 4; base < N; base += gridDim.x * 4) {
        const int n = base + wid;
        const bool active = (n < N);
        if (active) {
            const float4* mr = (const float4*)(magg + (size_t)n * DFEAT);
            if (lane < 40) ((float4*)sM[wid])[lane] = mr[lane];
        }
        __syncthreads();
        if (active) {
            const float* ms = sM[wid];
            const float* mv = sM[wid] + 64;
            const size_t o = (size_t)n * DFEAT;

            float acc = 0.f;
            #pragma unroll
            for (int u = 0; u < 64; ++u) acc += ms[u] * sWs[u * 64 + lane];
            out[o + lane] = x[o + lane] + fmaxf(kLS * acc, 0.f);

            const int w = lane & 31;
            {
                const int i0 = lane >> 5;
                float a = 0.f;
                #pragma unroll
                for (int u = 0; u < 32; ++u) a += mv[3 * u + i0] * sWv[u * 32 + w];
                out[o + 64 + 3 * w + i0] = x[o + 64 + 3 * w + i0] + fmaxf(kLV * a, 0.f);
            }
            if (lane < 32) {
                float a = 0.f;
                #pragma unroll
                for (int u = 0; u < 32; ++u) a += mv[3 * u + 2] * sWv[u * 32 + w];
                out[o + 64 + 3 * w + 2] = x[o + 64 + 3 * w + 2] + fmaxf(kLV * a, 0.f);
            }
        }
        __syncthreads();
    }
}

extern "C" void kernel_launch(void* const* d_in, const int* in_sizes, int n_in,
                              void* d_out, int out_size, void* d_ws, size_t ws_size,
                              hipStream_t stream) {
    const float* x  = (const float*)d_in[0];
    const float* sh = (const float*)d_in[1];
    const float* W1 = (const float*)d_in[2];
    const float* W2 = (const float*)d_in[3];
    const float* W3 = (const float*)d_in[4];
    const float* W4 = (const float*)d_in[5];
    const float* W5 = (const float*)d_in[6];
    const float* Ws = (const float*)d_in[7];
    const float* Wv = (const float*)d_in[8];
    const int*   ei = (const int*)d_in[9];

    const int E = in_sizes[9] / 2;
    const int N = in_sizes[0] / DFEAT;
    const int* src = ei;
    const int* dst = ei + E;

    float* magg = (float*)d_ws;  // N*160 floats = 32 MB
    hipMemsetAsync(magg, 0, (size_t)N * DFEAT * sizeof(float), stream);

    edge_kernel<<<1024, 256, 0, stream>>>(x, sh, W1, W2, W3, W4, W5, src, dst, magg, E);
    node_kernel<<<1024, 256, 0, stream>>>(x, magg, Ws, Wv, (float*)d_out, N);
}

// Round 7
// 482.072 us; speedup vs baseline: 72.8651x; 1.4851x over previous
//
#include <hip/hip_runtime.h>
#include <hip/hip_bf16.h>

#define MUL0 64
#define MUL1 32
#define DFEAT 160

typedef float  f4v __attribute__((ext_vector_type(4)));
typedef short  s8v __attribute__((ext_vector_type(8)));

__device__ __constant__ float kINV3 = 0.57735026918962576451f;  // 1/sqrt(3)
__device__ __constant__ float kINV6 = 0.40824829046386301637f;  // 1/sqrt(6)
__device__ __constant__ float kC0   = 0.10206207261596575f;     // 1/sqrt(96)
__device__ __constant__ float kC1   = 0.15309310892394863f;     // sqrt(3/128)
__device__ __constant__ float kLS   = 0.125f;                   // 1/sqrt(64)
__device__ __constant__ float kLV   = 0.17677669529663687f;     // 1/sqrt(32)

#define WAVE_SYNC() do { \
    asm volatile("s_waitcnt lgkmcnt(0)" ::: "memory"); \
    __builtin_amdgcn_sched_barrier(0); \
} while (0)

#define MFMA(a, b, c) __builtin_amdgcn_mfma_f32_16x16x32_bf16((a), (b), (c), 0, 0, 0)

// float -> bf16 bits, round-to-nearest-even (normal values)
__device__ __forceinline__ unsigned f2bf(float f) {
    const unsigned u = __builtin_bit_cast(unsigned, f);
    const unsigned r = 0x7fffu + ((u >> 16) & 1u);
    return (u + r) >> 16;
}
__device__ __forceinline__ unsigned pkbf(float a, float b) {
    return f2bf(a) | (f2bf(b) << 16);
}
__device__ __forceinline__ s8v mk8(float f0, float f1, float f2, float f3,
                                   float f4, float f5, float f6, float f7) {
    union { s8v v; unsigned u[4]; } r;
    r.u[0] = pkbf(f0, f1); r.u[1] = pkbf(f2, f3);
    r.u[2] = pkbf(f4, f5); r.u[3] = pkbf(f6, f7);
    return r.v;
}

// Pre-transpose weights to bf16 WT[N][K] (B-operand layout).
// wt layout: WT1[64][64] @0, WT2[64][32] @4096, WT3[32][64] @6144,
//            WT4[32][32] @8192, WT5[32][32] @9216  (10240 ushort total)
__global__ void wt_prep(const float* __restrict__ W1, const float* __restrict__ W2,
                        const float* __restrict__ W3, const float* __restrict__ W4,
                        const float* __restrict__ W5, unsigned short* __restrict__ wt)
{
    const int t = blockIdx.x * 256 + threadIdx.x;
    float v;
    if (t < 4096)       { int i = t;        v = W1[(i & 63) * 64 + (i >> 6)]; }       // n=i>>6,k=i&63
    else if (t < 6144)  { int i = t - 4096; v = W2[(i & 31) * 64 + (i >> 5)]; }       // [64][32]
    else if (t < 8192)  { int i = t - 6144; v = W3[(i & 63) * 32 + (i >> 6)]; }       // [32][64]
    else if (t < 9216)  { int i = t - 8192; v = W4[(i & 31) * 32 + (i >> 5)]; }
    else if (t < 10240) { int i = t - 9216; v = W5[(i & 31) * 32 + (i >> 5)]; }
    else return;
    wt[t] = (unsigned short)f2bf(v);
}

// 16 edges per wave via MFMA. A row = edge = lane&15 (per-edge scalars folded
// into A). D layout (m89): col=lane&15, row=(lane>>4)*4+reg. Flush via the
// round-5 LDS transpose -> coalesced atomics.
__global__ __launch_bounds__(256) void edge_kernel(
    const float* __restrict__ x, const float* __restrict__ sh,
    const int* __restrict__ src, const int* __restrict__ dst,
    const unsigned short* wt, float* magg, int E)
{
    __shared__ float sT[4][1552];
    __shared__ float sSh[4][4][16];

    const int tid  = threadIdx.x;
    const int lane = tid & 63;
    const int wid  = tid >> 6;
    const int l15  = lane & 15;
    const int pp   = lane >> 4;
    float* slab = sT[wid];

    const unsigned short* wt1 = wt;
    const unsigned short* wt2 = wt + 4096;
    const unsigned short* wt3 = wt + 6144;
    const unsigned short* wt4 = wt + 8192;
    const unsigned short* wt5 = wt + 9216;

    const int ntiles = (E + 15) >> 4;
    for (int tile = blockIdx.x * 4 + wid; tile < ntiles; tile += gridDim.x * 4) {
        const int ebase = tile << 4;
        const int eidx  = ebase + l15;
        const int ecl   = (eidx < E) ? eidx : (E - 1);
        const int didx  = (eidx < E) ? dst[ecl] : -1;
        const float4 she = ((const float4*)sh)[ecl];
        const float e0 = she.x, e1x = she.y, e1y = she.z, e1z = she.w;
        if (lane < 16) {
            sSh[wid][0][lane] = e0;  sSh[wid][1][lane] = e1x;
            sSh[wid][2][lane] = e1y; sSh[wid][3][lane] = e1z;
        }

        // ---- gather this lane's k-slices of its edge's x-row
        const float4* xq = (const float4*)(x + (size_t)src[ecl] * DFEAT);
        const float4 s0a = xq[2 * pp + 0], s0b = xq[2 * pp + 1];      // ss[8p..8p+7]
        const float4 s1a = xq[8 + 2 * pp], s1b = xq[9 + 2 * pp];      // ss[32+8p..]
        const float4 v0 = xq[16 + 6 * pp + 0], v1 = xq[16 + 6 * pp + 1];
        const float4 v2 = xq[16 + 6 * pp + 2], v3 = xq[16 + 6 * pp + 3];
        const float4 v4 = xq[16 + 6 * pp + 4], v5 = xq[16 + 6 * pp + 5];

        const float ssv[16] = { s0a.x, s0a.y, s0a.z, s0a.w, s0b.x, s0b.y, s0b.z, s0b.w,
                                s1a.x, s1a.y, s1a.z, s1a.w, s1b.x, s1b.y, s1b.z, s1b.w };
        const float vvv[24] = { v0.x, v0.y, v0.z, v0.w, v1.x, v1.y, v1.z, v1.w,
                                v2.x, v2.y, v2.z, v2.w, v3.x, v3.y, v3.z, v3.w,
                                v4.x, v4.y, v4.z, v4.w, v5.x, v5.y, v5.z, v5.w };

        float du[8], cx[8], cy[8], cz[8];
        #pragma unroll
        for (int j = 0; j < 8; ++j) {
            const float vx = vvv[3 * j], vy = vvv[3 * j + 1], vz = vvv[3 * j + 2];
            du[j] = vx * e1x + vy * e1y + vz * e1z;
            cx[j] = vy * e1z - vz * e1y;
            cy[j] = vz * e1x - vx * e1z;
            cz[j] = vx * e1y - vy * e1x;
        }

        // ================= group 1: out0 =================
        const float sA = kC0 * e0;
        const float sD = kC0 * kINV3;
        const s8v aS0 = mk8(ssv[0]*sA, ssv[1]*sA, ssv[2]*sA, ssv[3]*sA,
                            ssv[4]*sA, ssv[5]*sA, ssv[6]*sA, ssv[7]*sA);
        const s8v aS1 = mk8(ssv[8]*sA, ssv[9]*sA, ssv[10]*sA, ssv[11]*sA,
                            ssv[12]*sA, ssv[13]*sA, ssv[14]*sA, ssv[15]*sA);
        const s8v aD  = mk8(du[0]*sD, du[1]*sD, du[2]*sD, du[3]*sD,
                            du[4]*sD, du[5]*sD, du[6]*sD, du[7]*sD);

        f4v acc0[4];
        #pragma unroll
        for (int nt = 0; nt < 4; ++nt) acc0[nt] = (f4v){0.f, 0.f, 0.f, 0.f};
        #pragma unroll
        for (int nt = 0; nt < 4; ++nt) {
            const int row = (16 * nt + l15);
            s8v b;
            b = *(const s8v*)(wt1 + row * 64 + 0  + 8 * pp);  acc0[nt] = MFMA(aS0, b, acc0[nt]);
            b = *(const s8v*)(wt1 + row * 64 + 32 + 8 * pp);  acc0[nt] = MFMA(aS1, b, acc0[nt]);
            b = *(const s8v*)(wt2 + row * 32 + 8 * pp);       acc0[nt] = MFMA(aD,  b, acc0[nt]);
        }

        WAVE_SYNC();  // prev-tile flush reads done; she stash visible

        // out0 -> LDS transpose tile [16][64], col swizzle (c+edge)&63
        #pragma unroll
        for (int nt = 0; nt < 4; ++nt)
            #pragma unroll
            for (int jj = 0; jj < 4; ++jj) {
                const int ed = 4 * pp + jj;
                slab[64 * ed + ((16 * nt + l15 + ed) & 63)] = acc0[nt][jj];
            }
        WAVE_SYNC();
        for (int q = 0; q < 16; ++q) {
            const int dq = __builtin_amdgcn_readlane(didx, q);
            if (dq >= 0)
                atomicAdd(&magg[(size_t)dq * DFEAT + lane], slab[64 * q + ((lane + q) & 63)]);
        }

        // ================= group 2: out1 =================
        const s8v aR0 = mk8(ssv[0], ssv[1], ssv[2], ssv[3], ssv[4], ssv[5], ssv[6], ssv[7]);
        const s8v aR1 = mk8(ssv[8], ssv[9], ssv[10], ssv[11], ssv[12], ssv[13], ssv[14], ssv[15]);
        const float sV = kC1 * kINV3 * e0;
        const float sC = kC1 * kINV6;
        const s8v aVx = mk8(vvv[0]*sV, vvv[3]*sV, vvv[6]*sV, vvv[9]*sV,
                            vvv[12]*sV, vvv[15]*sV, vvv[18]*sV, vvv[21]*sV);
        const s8v aVy = mk8(vvv[1]*sV, vvv[4]*sV, vvv[7]*sV, vvv[10]*sV,
                            vvv[13]*sV, vvv[16]*sV, vvv[19]*sV, vvv[22]*sV);
        const s8v aVz = mk8(vvv[2]*sV, vvv[5]*sV, vvv[8]*sV, vvv[11]*sV,
                            vvv[14]*sV, vvv[17]*sV, vvv[20]*sV, vvv[23]*sV);
        const s8v aCx = mk8(cx[0]*sC, cx[1]*sC, cx[2]*sC, cx[3]*sC,
                            cx[4]*sC, cx[5]*sC, cx[6]*sC, cx[7]*sC);
        const s8v aCy = mk8(cy[0]*sC, cy[1]*sC, cy[2]*sC, cy[3]*sC,
                            cy[4]*sC, cy[5]*sC, cy[6]*sC, cy[7]*sC);
        const s8v aCz = mk8(cz[0]*sC, cz[1]*sC, cz[2]*sC, cz[3]*sC,
                            cz[4]*sC, cz[5]*sC, cz[6]*sC, cz[7]*sC);

        f4v accS[2], accO0[2], accO1[2], accO2[2];
        #pragma unroll
        for (int nt = 0; nt < 2; ++nt) {
            accS[nt] = (f4v){0.f,0.f,0.f,0.f};
            accO0[nt] = (f4v){0.f,0.f,0.f,0.f};
            accO1[nt] = (f4v){0.f,0.f,0.f,0.f};
            accO2[nt] = (f4v){0.f,0.f,0.f,0.f};
        }
        #pragma unroll
        for (int nt = 0; nt < 2; ++nt) {
            const int row = (16 * nt + l15);
            s8v b;
            b = *(const s8v*)(wt3 + row * 64 + 0  + 8 * pp);  accS[nt] = MFMA(aR0, b, accS[nt]);
            b = *(const s8v*)(wt3 + row * 64 + 32 + 8 * pp);  accS[nt] = MFMA(aR1, b, accS[nt]);
            b = *(const s8v*)(wt4 + row * 32 + 8 * pp);
            accO0[nt] = MFMA(aVx, b, accO0[nt]);
            accO1[nt] = MFMA(aVy, b, accO1[nt]);
            accO2[nt] = MFMA(aVz, b, accO2[nt]);
            b = *(const s8v*)(wt5 + row * 32 + 8 * pp);
            accO0[nt] = MFMA(aCx, b, accO0[nt]);
            accO1[nt] = MFMA(aCy, b, accO1[nt]);
            accO2[nt] = MFMA(aCz, b, accO2[nt]);
        }

        WAVE_SYNC();  // out0 flush slab reads done before overwrite
        const float s3f = kC1 * kINV3;
        float e1d0[4], e1d1[4], e1d2[4];
        #pragma unroll
        for (int jj = 0; jj < 4; ++jj) {
            const int ed = 4 * pp + jj;
            e1d0[jj] = sSh[wid][1][ed];
            e1d1[jj] = sSh[wid][2][ed];
            e1d2[jj] = sSh[wid][3][ed];
        }
        #pragma unroll
        for (int nt = 0; nt < 2; ++nt)
            #pragma unroll
            for (int jj = 0; jj < 4; ++jj) {
                const int ed = 4 * pp + jj;
                const int cb = 3 * (16 * nt + l15);
                const float s3 = s3f * accS[nt][jj];
                slab[97 * ed + cb + 0] = accO0[nt][jj] + e1d0[jj] * s3;
                slab[97 * ed + cb + 1] = accO1[nt][jj] + e1d1[jj] * s3;
                slab[97 * ed + cb + 2] = accO2[nt][jj] + e1d2[jj] * s3;
            }
        WAVE_SYNC();
        for (int q = 0; q < 16; ++q) {
            const int dq = __builtin_amdgcn_readlane(didx, q);
            if (dq >= 0) {
                float* b = &magg[(size_t)dq * DFEAT + 64];
                atomicAdd(b + lane, slab[97 * q + lane]);
                if (lane < 32)
                    atomicAdd(b + 64 + lane, slab[97 * q + 64 + lane]);
            }
        }
        WAVE_SYNC();  // flush reads done before next tile's slab writes
    }
}

// One wave per node: h = [m_s@Ws*LS ; (m_v@Wv)*LV], out = x + relu(h)
__global__ __launch_bounds__(256) void node_kernel(
    const float* __restrict__ x, const float* __restrict__ magg,
    const float* __restrict__ Ws, const float* __restrict__ Wv,
    float* __restrict__ out, int N)
{
    __shared__ float sWs[64 * 64];
    __shared__ float sWv[32 * 32];
    __shared__ float sM[4][DFEAT];

    const int tid = threadIdx.x;
    for (int i = tid; i < 64 * 64; i += 256) sWs[i] = Ws[i];
    for (int i = tid; i < 32 * 32; i += 256) sWv[i] = Wv[i];
    __syncthreads();

    const int lane = tid & 63;
    const int wid  = tid >> 6;

    for (int base = blockIdx.x * 4; base < N; base += gridDim.x * 4) {
        const int n = base + wid;
        const bool active = (n < N);
        if (active) {
            const float4* mr = (const float4*)(magg + (size_t)n * DFEAT);
            if (lane < 40) ((float4*)sM[wid])[lane] = mr[lane];
        }
        __syncthreads();
        if (active) {
            const float* ms = sM[wid];
            const float* mv = sM[wid] + 64;
            const size_t o = (size_t)n * DFEAT;

            float acc = 0.f;
            #pragma unroll
            for (int u = 0; u < 64; ++u) acc += ms[u] * sWs[u * 64 + lane];
            out[o + lane] = x[o + lane] + fmaxf(kLS * acc, 0.f);

            const int w = lane & 31;
            {
                const int i0 = lane >> 5;
                float a = 0.f;
                #pragma unroll
                for (int u = 0; u < 32; ++u) a += mv[3 * u + i0] * sWv[u * 32 + w];
                out[o + 64 + 3 * w + i0] = x[o + 64 + 3 * w + i0] + fmaxf(kLV * a, 0.f);
            }
            if (lane < 32) {
                float a = 0.f;
                #pragma unroll
                for (int u = 0; u < 32; ++u) a += mv[3 * u + 2] * sWv[u * 32 + w];
                out[o + 64 + 3 * w + 2] = x[o + 64 + 3 * w + 2] + fmaxf(kLV * a, 0.f);
            }
        }
        __syncthreads();
    }
}

extern "C" void kernel_launch(void* const* d_in, const int* in_sizes, int n_in,
                              void* d_out, int out_size, void* d_ws, size_t ws_size,
                              hipStream_t stream) {
    const float* x  = (const float*)d_in[0];
    const float* sh = (const float*)d_in[1];
    const float* W1 = (const float*)d_in[2];
    const float* W2 = (const float*)d_in[3];
    const float* W3 = (const float*)d_in[4];
    const float* W4 = (const float*)d_in[5];
    const float* W5 = (const float*)d_in[6];
    const float* Ws = (const float*)d_in[7];
    const float* Wv = (const float*)d_in[8];
    const int*   ei = (const int*)d_in[9];

    const int E = in_sizes[9] / 2;
    const int N = in_sizes[0] / DFEAT;
    const int* src = ei;
    const int* dst = ei + E;

    float* magg = (float*)d_ws;                                        // N*160 f32 = 32 MB
    unsigned short* wt = (unsigned short*)(magg + (size_t)N * DFEAT);  // 10240 bf16

    (void)hipMemsetAsync(magg, 0, (size_t)N * DFEAT * sizeof(float), stream);
    wt_prep<<<40, 256, 0, stream>>>(W1, W2, W3, W4, W5, wt);
    edge_kernel<<<1024, 256, 0, stream>>>(x, sh, src, dst, wt, magg, E);
    node_kernel<<<1024, 256, 0, stream>>>(x, magg, Ws, Wv, (float*)d_out, N);
}